// Round 1
// baseline (477.686 us; speedup 1.0000x reference)
//
#include <hip/hip_runtime.h>

// DeltaModulationEncoder: x (16, 256, 8192) f32 -> spikes {-1,0,1} f32, same shape.
// Sequential scan per channel over T. Parallelized over time via speculative
// segments + exact verification/fixup (see comments).

constexpr float TH   = 0.1f;
constexpr int   T    = 8192;
constexpr int   NCH  = 16 * 256;   // 4096 independent channels
constexpr int   SEG  = 512;        // segment length (time steps)
constexpr int   NSEG = T / SEG;    // 16 segments per channel
constexpr int   W    = 128;        // warm-up lookback steps for state coalescence

// One delta-modulation step, bit-exact vs the reference f32 semantics:
//   err = x - recon; net = (err>th) - (err<-th); recon += net*th; spike = net
// nth = net*th is exact (0, +0.1f, -0.1f); recon update is a single f32 add
// (matches reference's recon + net*th, incl. the net==0 "+0.0f" case).
// spike = nth*10.0f rounds exactly to {-1.0f, 0.0f, 1.0f}.
__device__ __forceinline__ void dm_step(float xv, float& recon, float& spike) {
    float err = xv - recon;
    float nth = 0.0f;
    nth = (err > TH)  ?  TH : nth;
    nth = (err < -TH) ? -TH : nth;
    recon += nth;
    spike = nth * 10.0f;
}

__device__ __forceinline__ void proc4(const float4 c, float& recon, float4& s) {
    dm_step(c.x, recon, s.x);
    dm_step(c.y, recon, s.y);
    dm_step(c.z, recon, s.z);
    dm_step(c.w, recon, s.w);
}

// Process nchunk chunks of 16 elements (4 x float4) with a 1-chunk-deep
// software pipeline: next chunk's 4 loads (64 B/lane) are in flight while the
// current 16-step dependent ALU chain runs. 65536 threads x 64 B = 4 MB in
// flight -> HBM-BW-bound, not latency-bound.
template<bool STORE>
__device__ __forceinline__ float run_span(const float4* __restrict__ pin,
                                          float4* __restrict__ pout,
                                          int nchunk, float recon) {
    float4 c0 = pin[0], c1 = pin[1], c2 = pin[2], c3 = pin[3];
    for (int k = 0; k < nchunk; ++k) {
        float4 n0, n1, n2, n3;
        if (k + 1 < nchunk) {
            const float4* p = pin + 4 * (k + 1);
            n0 = p[0]; n1 = p[1]; n2 = p[2]; n3 = p[3];
        }
        float4 s0, s1, s2, s3;
        proc4(c0, recon, s0);
        proc4(c1, recon, s1);
        proc4(c2, recon, s2);
        proc4(c3, recon, s3);
        if (STORE) {
            float4* q = pout + 4 * k;
            q[0] = s0; q[1] = s1; q[2] = s2; q[3] = s3;
        }
        c0 = n0; c1 = n1; c2 = n2; c3 = n3;
    }
    return recon;
}

// Round 0: one thread per (channel, segment). Segment 0 starts exactly at 0.
// Segments s>0 warm up over the previous W samples from guess recon=0 (the
// tracker is contracting; fp trajectories coalesce bitwise w.h.p.), then
// record the entry state actually used and the end state.
__global__ __launch_bounds__(256) void dm_round0(const float* __restrict__ x,
                                                 float* __restrict__ out,
                                                 float* __restrict__ end_st,
                                                 float* __restrict__ entry_st) {
    int tid = blockIdx.x * 256 + threadIdx.x;   // tid = ch*NSEG + s
    int s   = tid & (NSEG - 1);
    int ch  = tid >> 4;                          // log2(NSEG) == 4
    const float* px = x   + (size_t)ch * T + (size_t)s * SEG;
    float*       po = out + (size_t)ch * T + (size_t)s * SEG;

    float recon = 0.0f;
    if (s != 0) {
        recon = run_span<false>((const float4*)(px - W), nullptr, W / 16, 0.0f);
    }
    entry_st[tid] = recon;
    recon = run_span<true>((const float4*)px, (float4*)po, SEG / 16, recon);
    end_st[tid] = recon;
}

// Fixup: one thread per channel walks the segment chain with the exactly-known
// state v. If a segment's recorded entry equals v (float equality), its round-0
// spikes came from the identical state -> bit-exact (deterministic ops), and
// end_st is the exact next state. Otherwise recompute that segment from v.
// Exact by induction regardless of coalescence behavior; expected near no-op.
__global__ __launch_bounds__(256) void dm_fixup(const float* __restrict__ x,
                                                float* __restrict__ out,
                                                const float* __restrict__ end_st,
                                                const float* __restrict__ entry_st) {
    int ch = blockIdx.x * 256 + threadIdx.x;
    if (ch >= NCH) return;
    float v = end_st[(size_t)ch * NSEG];  // segment 0 is always exact
    for (int s = 1; s < NSEG; ++s) {
        int idx = ch * NSEG + s;
        if (entry_st[idx] == v) {
            v = end_st[idx];
        } else {
            const float4* pin  = (const float4*)(x   + (size_t)ch * T + (size_t)s * SEG);
            float4*       pout = (float4*)      (out + (size_t)ch * T + (size_t)s * SEG);
            v = run_span<true>(pin, pout, SEG / 16, v);
        }
    }
}

// Safety fallback if the workspace is too small for the state arrays:
// plain one-thread-per-channel sequential scan (correct, slower).
__global__ __launch_bounds__(256) void dm_sequential(const float* __restrict__ x,
                                                     float* __restrict__ out) {
    int ch = blockIdx.x * 256 + threadIdx.x;
    if (ch >= NCH) return;
    const float4* pin  = (const float4*)(x   + (size_t)ch * T);
    float4*       pout = (float4*)      (out + (size_t)ch * T);
    run_span<true>(pin, pout, T / 16, 0.0f);
}

extern "C" void kernel_launch(void* const* d_in, const int* in_sizes, int n_in,
                              void* d_out, int out_size, void* d_ws, size_t ws_size,
                              hipStream_t stream) {
    const float* x   = (const float*)d_in[0];
    float*       out = (float*)d_out;

    size_t st_elems = (size_t)NCH * NSEG;           // 65536 floats per array
    if (ws_size < 2 * st_elems * sizeof(float)) {
        dm_sequential<<<NCH / 256, 256, 0, stream>>>(x, out);
        return;
    }
    float* end_st   = (float*)d_ws;
    float* entry_st = end_st + st_elems;

    dm_round0<<<(NCH * NSEG) / 256, 256, 0, stream>>>(x, out, end_st, entry_st);
    dm_fixup<<<NCH / 256, 256, 0, stream>>>(x, out, end_st, entry_st);
}